// Round 5
// baseline (257.585 us; speedup 1.0000x reference)
//
#include <hip/hip_runtime.h>

typedef _Float16 f16;
typedef __attribute__((ext_vector_type(8))) _Float16 f16x8;
typedef __attribute__((ext_vector_type(4))) _Float16 f16x4;
typedef __attribute__((ext_vector_type(4))) float f32x4;

namespace {
constexpr int kL   = 65536;
constexpr int kR   = 256;
constexpr int kD   = 64;
constexpr int kDV  = 64;

constexpr int kABlocks = 512;   // 128 cols each (2 chunks of 64)
constexpr int kAChunks = 2;
constexpr int kBBlocks = 1024;  // 64 cols each

// Instrumentation: idempotent internal repeats so each kernel's dispatch
// exceeds the 40us harness fills and lands in rocprof top-5 with counters.
constexpr int kRepA = 8;
constexpr int kRepR = 16;
constexpr int kRepB = 8;

constexpr float kAc  = 0.1f;
constexpr float kBc  = 0.7745966692414834f;      // sqrt(0.6)
constexpr float kDnS = 0.2888816545234944f;      // 0.6^16 * 2^10 (PHI_SCALE folded)
constexpr float kOutScale = 9.5367431640625e-7f; // 2^-20 undoes PHI_SCALE^2
}

// ---------------------------------------------------------------------------
// Kernel A: partials[blk][dv][r] (f16) = (phi(K_cols)*2^10 @ V_cols)^T
// ---------------------------------------------------------------------------
__global__ __launch_bounds__(512, 2)
void favor_kv(const float* __restrict__ Kg, const float* __restrict__ Vg,
              const float* __restrict__ Wg, f16* __restrict__ partials)
{
    __shared__ f16 sXt[64 * 64];    // K chunk [l][d], swizzled
    __shared__ f16 sVt[64 * 64];    // V chunk [dv][l], swizzled
    __shared__ f16 sPhi[256 * 64];  // [r][l], swizzled
    __shared__ float sRed[8 * 64];  // per-wave norm partials
    __shared__ float sRedT[64];     // total column norms

    const int tid  = threadIdx.x;
    const int w    = tid >> 6;
    const int lane = tid & 63;
    const int l15  = lane & 15;
    const int lhi  = lane >> 4;
    const int blk  = blockIdx.x;
    const int lblk = blk * (64 * kAChunks);

    // W fragments; used as the B-operand (col = l15 -> r, k = 8*lhi+j -> d).
    f16x8 wfrag[2][2];
#pragma unroll
    for (int ri = 0; ri < 2; ++ri)
#pragma unroll
        for (int ks = 0; ks < 2; ++ks) {
            const float* p = Wg + (32 * w + 16 * ri + l15) * kD + 32 * ks + 8 * lhi;
            f16x8 v;
#pragma unroll
            for (int j = 0; j < 8; ++j) v[j] = (f16)p[j];
            wfrag[ri][ks] = v;
        }

    const int wr = w >> 1;     // PV r-group (64 rows)
    const int wc = w & 1;      // PV dv half (32 cols)
    const int scol  = lane;
    const int dbase = w * 8;

#pragma unroll 1
    for (int rep = 0; rep < kRepA; ++rep) {
        f32x4 acc[4][2];
#pragma unroll
        for (int a = 0; a < 4; ++a)
#pragma unroll
            for (int d = 0; d < 2; ++d) { f32x4 z0 = {0.f, 0.f, 0.f, 0.f}; acc[a][d] = z0; }

#pragma unroll 1
        for (int t = 0; t < kAChunks; ++t) {
            const int l0 = lblk + t * 64;

            // ---- stage K,V (f32 -> f16, transposed, swizzled) + norm partials
            {
                float s = 0.f;
                f16x8 hk, hv;
#pragma unroll
                for (int j = 0; j < 8; ++j) {
                    const float x = Kg[(dbase + j) * kL + l0 + scol];
                    s += x * x;
                    hk[j] = (f16)x;
                }
#pragma unroll
                for (int j = 0; j < 8; ++j)
                    hv[j] = (f16)Vg[(size_t)(l0 + dbase + j) * kDV + scol];
                sRed[w * 64 + scol] = s;
                *(f16x8*)&sXt[scol * 64 + (dbase ^ ((scol & 7) << 3))] = hk;
                *(f16x8*)&sVt[scol * 64 + (dbase ^ ((scol & 7) << 3))] = hv;
            }
            __syncthreads();

            // column norms; every wave computes + writes identical sRedT (benign)
            {
                float sqv = 0.f;
#pragma unroll
                for (int g = 0; g < 8; ++g) sqv += sRed[g * 64 + lane];
                sRedT[lane] = sqv;
            }

            // ---- z = K^T W^T per ri: C[l][r]; then phi packed along l
#pragma unroll
            for (int ri = 0; ri < 2; ++ri) {
                f32x4 z[4];
#pragma unroll
                for (int lf = 0; lf < 4; ++lf) { f32x4 z0 = {0.f, 0.f, 0.f, 0.f}; z[lf] = z0; }
#pragma unroll
                for (int ks = 0; ks < 2; ++ks) {
                    f16x8 bfr[4];
#pragma unroll
                    for (int lf = 0; lf < 4; ++lf) {
                        const int row = 16 * lf + l15;
                        bfr[lf] = *(const f16x8*)&sXt[row * 64 + ((32 * ks + 8 * lhi) ^ ((row & 7) << 3))];
                    }
#pragma unroll
                    for (int lf = 0; lf < 4; ++lf)
                        z[lf] = __builtin_amdgcn_mfma_f32_16x16x32_f16(bfr[lf], wfrag[ri][ks], z[lf], 0, 0, 0);
                }
                const int r = 32 * w + 16 * ri + l15;
#pragma unroll
                for (int lf = 0; lf < 4; ++lf) {
                    const f32x4 sq4 = *(const f32x4*)&sRedT[16 * lf + 4 * lhi];
                    f16x4 ph;
#pragma unroll
                    for (int j = 0; j < 4; ++j)
                        ph[j] = (f16)(kDnS * __expf(kAc + kBc * z[lf][j] - sq4[j]));
                    const int lbase = 16 * lf + 4 * lhi;
                    *(f16x4*)&sPhi[r * 64 + (lbase ^ ((r & 7) << 3))] = ph;
                }
            }
            __syncthreads();

            // ---- acc += phi @ V
#pragma unroll
            for (int ks = 0; ks < 2; ++ks) {
                f16x8 af[4], bf[2];
#pragma unroll
                for (int ai = 0; ai < 4; ++ai) {
                    const int r = 64 * wr + 16 * ai + l15;
                    af[ai] = *(const f16x8*)&sPhi[r * 64 + ((32 * ks + 8 * lhi) ^ ((r & 7) << 3))];
                }
#pragma unroll
                for (int di = 0; di < 2; ++di) {
                    const int dv = 32 * wc + 16 * di + l15;
                    bf[di] = *(const f16x8*)&sVt[dv * 64 + ((32 * ks + 8 * lhi) ^ ((dv & 7) << 3))];
                }
#pragma unroll
                for (int ai = 0; ai < 4; ++ai)
#pragma unroll
                    for (int di = 0; di < 2; ++di)
                        acc[ai][di] = __builtin_amdgcn_mfma_f32_16x16x32_f16(af[ai], bf[di], acc[ai][di], 0, 0, 0);
            }
            __syncthreads();
        }

        // ---- per-block partial, stored TRANSPOSED [dv][r]
        f16* po = partials + (size_t)blk * (kR * kDV);
#pragma unroll
        for (int ai = 0; ai < 4; ++ai)
#pragma unroll
            for (int di = 0; di < 2; ++di) {
                const int dv = 32 * wc + 16 * di + l15;
                f16x4 pk;
#pragma unroll
                for (int j = 0; j < 4; ++j) pk[j] = (f16)acc[ai][di][j];
                *(f16x4*)&po[dv * kR + 64 * wr + 16 * ai + 4 * lhi] = pk;
            }
    }
}

// ---------------------------------------------------------------------------
// Kernel R: kvT[o] = sum over 512 slices of partials[s][o]   (o = dv*256 + r)
// ---------------------------------------------------------------------------
__global__ __launch_bounds__(512)
void favor_reduce(const f16* __restrict__ partials, f16* __restrict__ kvT)
{
    __shared__ float sAcc[8][512];
    const int tid  = threadIdx.x;
    const int w    = tid >> 6;
    const int lane = tid & 63;
    const size_t obase = (size_t)blockIdx.x * 512 + lane * 8;

#pragma unroll 1
    for (int rep = 0; rep < kRepR; ++rep) {
        float a[8] = {0.f, 0.f, 0.f, 0.f, 0.f, 0.f, 0.f, 0.f};
#pragma unroll 8
        for (int i = 0; i < 64; ++i) {
            const int s = w * 64 + i;
            const f16x8 v = *(const f16x8*)&partials[(size_t)s * (kR * kDV) + obase];
#pragma unroll
            for (int j = 0; j < 8; ++j) a[j] += (float)v[j];
        }
#pragma unroll
        for (int j = 0; j < 8; ++j) sAcc[w][lane * 8 + j] = a[j];
        __syncthreads();

        float tot = 0.f;
#pragma unroll
        for (int g = 0; g < 8; ++g) tot += sAcc[g][tid];
        kvT[(size_t)blockIdx.x * 512 + tid] = (f16)tot;
        __syncthreads();
    }
}

// ---------------------------------------------------------------------------
// Kernel B: out = (phi(Q)*2^10)^T @ kv, scaled 2^-20. 1024 blocks, 64 cols.
// ---------------------------------------------------------------------------
__global__ __launch_bounds__(512, 2)
void favor_out(const float* __restrict__ Qg, const float* __restrict__ Wg,
               const f16* __restrict__ kvT, float* __restrict__ outg)
{
    __shared__ f16 sXt[64 * 64];     // Q chunk [l][d]
    __shared__ f16 sPhiT[64 * 256];  // [l][r]
    __shared__ float sRed[8 * 64];

    const int tid  = threadIdx.x;
    const int w    = tid >> 6;
    const int lane = tid & 63;
    const int l15  = lane & 15;
    const int lhi  = lane >> 4;
    const int l0   = blockIdx.x * 64;

    f16x8 wfrag[2][2];
#pragma unroll
    for (int ri = 0; ri < 2; ++ri)
#pragma unroll
        for (int ks = 0; ks < 2; ++ks) {
            const float* p = Wg + (32 * w + 16 * ri + l15) * kD + 32 * ks + 8 * lhi;
            f16x8 v;
#pragma unroll
            for (int j = 0; j < 8; ++j) v[j] = (f16)p[j];
            wfrag[ri][ks] = v;
        }

    const int lfo = w >> 1;
    const int dvh = w & 1;

    // kv B-fragments from kvT[dv][r]
    f16x8 kvf[2][8];
#pragma unroll
    for (int di = 0; di < 2; ++di) {
        const int dv = 32 * dvh + 16 * di + l15;
#pragma unroll
        for (int ks = 0; ks < 8; ++ks)
            kvf[di][ks] = *(const f16x8*)&kvT[dv * kR + 32 * ks + 8 * lhi];
    }

#pragma unroll 1
    for (int rep = 0; rep < kRepB; ++rep) {
        // ---- stage Q + norms
        {
            const int scol  = lane;
            const int dbase = w * 8;
            float s = 0.f;
            f16x8 hq;
#pragma unroll
            for (int j = 0; j < 8; ++j) {
                const float x = Qg[(dbase + j) * kL + l0 + scol];
                s += x * x;
                hq[j] = (f16)x;
            }
            sRed[w * 64 + scol] = s;
            *(f16x8*)&sXt[scol * 64 + (dbase ^ ((scol & 7) << 3))] = hq;
        }
        __syncthreads();

        float sqv = 0.f;
#pragma unroll
        for (int g = 0; g < 8; ++g) sqv += sRed[g * 64 + lane];
        float sqs[4];
#pragma unroll
        for (int lf = 0; lf < 4; ++lf) sqs[lf] = __shfl(sqv, lf * 16 + l15, 64);

        // ---- z = W @ Q per ri: C[r][l]; phi packs 4 consecutive r -> [l][r]
#pragma unroll
        for (int ri = 0; ri < 2; ++ri) {
            f32x4 z[4];
#pragma unroll
            for (int lf = 0; lf < 4; ++lf) { f32x4 z0 = {0.f, 0.f, 0.f, 0.f}; z[lf] = z0; }
#pragma unroll
            for (int ks = 0; ks < 2; ++ks) {
                f16x8 bfr[4];
#pragma unroll
                for (int lf = 0; lf < 4; ++lf) {
                    const int row = 16 * lf + l15;
                    bfr[lf] = *(const f16x8*)&sXt[row * 64 + ((32 * ks + 8 * lhi) ^ ((row & 7) << 3))];
                }
#pragma unroll
                for (int lf = 0; lf < 4; ++lf)
                    z[lf] = __builtin_amdgcn_mfma_f32_16x16x32_f16(wfrag[ri][ks], bfr[lf], z[lf], 0, 0, 0);
            }
            const int r0 = 32 * w + 16 * ri + 4 * lhi;
#pragma unroll
            for (int lf = 0; lf < 4; ++lf) {
                const int lc = 16 * lf + l15;
                f16x4 ph;
#pragma unroll
                for (int j = 0; j < 4; ++j)
                    ph[j] = (f16)(kDnS * __expf(kAc + kBc * z[lf][j] - sqs[lf]));
                *(f16x4*)&sPhiT[lc * 256 + (r0 ^ ((lc & 7) << 3))] = ph;
            }
        }
        __syncthreads();

        // ---- out tile = phiQ^T @ kv
        f32x4 o2[2];
        { f32x4 z0 = {0.f, 0.f, 0.f, 0.f}; o2[0] = z0; o2[1] = z0; }
        const int lrow = 16 * lfo + l15;
#pragma unroll
        for (int ks = 0; ks < 8; ++ks) {
            const f16x8 af = *(const f16x8*)&sPhiT[lrow * 256 + ((32 * ks + 8 * lhi) ^ ((lrow & 7) << 3))];
#pragma unroll
            for (int di = 0; di < 2; ++di)
                o2[di] = __builtin_amdgcn_mfma_f32_16x16x32_f16(af, kvf[di][ks], o2[di], 0, 0, 0);
        }
#pragma unroll
        for (int di = 0; di < 2; ++di)
#pragma unroll
            for (int j = 0; j < 4; ++j) {
                const int ll = 16 * lfo + 4 * lhi + j;
                const int dv = 32 * dvh + 16 * di + l15;
                outg[(size_t)(l0 + ll) * kDV + dv] = o2[di][j] * kOutScale;
            }
        __syncthreads();
    }
}

extern "C" void kernel_launch(void* const* d_in, const int* in_sizes, int n_in,
                              void* d_out, int out_size, void* d_ws, size_t ws_size,
                              hipStream_t stream)
{
    const float* Q = (const float*)d_in[0];
    const float* K = (const float*)d_in[1];
    const float* V = (const float*)d_in[2];
    const float* W = (const float*)d_in[3];
    float* out = (float*)d_out;

    f16* partials = (f16*)d_ws;  // 512 * 16384 f16 = 16 MiB
    f16* kvT = (f16*)((char*)d_ws + (size_t)kABlocks * kR * kDV * sizeof(f16));

    favor_kv<<<kABlocks, 512, 0, stream>>>(K, V, W, partials);
    favor_reduce<<<32, 512, 0, stream>>>(partials, kvT);
    favor_out<<<kBBlocks, 512, 0, stream>>>(Q, W, kvT, out);

    (void)in_sizes; (void)n_in; (void)out_size; (void)ws_size;
}

// Round 6
// 42.275 us; speedup vs baseline: 6.0931x; 6.0931x over previous
//
#include <hip/hip_runtime.h>

typedef _Float16 f16;
typedef __attribute__((ext_vector_type(8))) _Float16 f16x8;
typedef __attribute__((ext_vector_type(4))) _Float16 f16x4;
typedef __attribute__((ext_vector_type(4))) float f32x4;

namespace {
constexpr int kL   = 65536;
constexpr int kR   = 256;
constexpr int kD   = 64;
constexpr int kDV  = 64;

constexpr int kABlocks = 512;   // 128 cols each (2 chunks of 64)
constexpr int kBBlocks = 512;   // 128 cols each (2 chunks of 64)
constexpr int kRBlocks = 128;   // 128 outputs each

constexpr float kAc  = 0.1f;
constexpr float kBc  = 0.7745966692414834f;      // sqrt(0.6)
constexpr float kDnS = 0.2888816545234944f;      // 0.6^16 * 2^10 (PHI_SCALE folded)
constexpr float kOutScale = 9.5367431640625e-7f; // 2^-20 undoes PHI_SCALE^2
}

// ---------------------------------------------------------------------------
// Kernel A: partials[blk][dv][r] (f16) = (phi(K_cols)*2^10 @ V_cols)^T
// Both chunks' K/V preloaded to registers at entry (loads in flight across
// chunk-0 compute); swapped-operand MFMA packs phi along l (b64 stores).
// ---------------------------------------------------------------------------
__global__ __launch_bounds__(512, 2)
void favor_kv(const float* __restrict__ Kg, const float* __restrict__ Vg,
              const float* __restrict__ Wg, f16* __restrict__ partials)
{
    __shared__ f16 sXt[64 * 64];    // K chunk [l][d], swizzled
    __shared__ f16 sVt[64 * 64];    // V chunk [dv][l], swizzled
    __shared__ f16 sPhi[256 * 64];  // [r][l], swizzled
    __shared__ float sRed[8 * 64];  // per-wave norm partials
    __shared__ float sRedT[64];     // total column norms

    const int tid  = threadIdx.x;
    const int w    = tid >> 6;
    const int lane = tid & 63;
    const int l15  = lane & 15;
    const int lhi  = lane >> 4;
    const int blk  = blockIdx.x;
    const int lblk = blk * 128;

    const int scol  = lane;
    const int dbase = w * 8;

    // ---- issue ALL global loads up front (FIFO vmcnt: chunk0 first)
    float ka[2][8], va[2][8];
#pragma unroll
    for (int c = 0; c < 2; ++c) {
        const int l0 = lblk + c * 64;
#pragma unroll
        for (int j = 0; j < 8; ++j) ka[c][j] = Kg[(dbase + j) * kL + l0 + scol];
#pragma unroll
        for (int j = 0; j < 8; ++j) va[c][j] = Vg[(size_t)(l0 + dbase + j) * kDV + scol];
    }

    // W fragments (B-operand: col = l15 -> r, k = 8*lhi+j -> d)
    f16x8 wfrag[2][2];
#pragma unroll
    for (int ri = 0; ri < 2; ++ri)
#pragma unroll
        for (int ks = 0; ks < 2; ++ks) {
            const float* p = Wg + (32 * w + 16 * ri + l15) * kD + 32 * ks + 8 * lhi;
            f16x8 v;
#pragma unroll
            for (int j = 0; j < 8; ++j) v[j] = (f16)p[j];
            wfrag[ri][ks] = v;
        }

    f32x4 acc[4][2];
#pragma unroll
    for (int a = 0; a < 4; ++a)
#pragma unroll
        for (int d = 0; d < 2; ++d) { f32x4 z0 = {0.f, 0.f, 0.f, 0.f}; acc[a][d] = z0; }

    const int wr = w >> 1;     // PV r-group (64 rows)
    const int wc = w & 1;      // PV dv half (32 cols)

#pragma unroll
    for (int c = 0; c < 2; ++c) {
        // ---- stage chunk c from regs (f32 -> f16, transposed, swizzled)
        {
            float s = 0.f;
            f16x8 hk, hv;
#pragma unroll
            for (int j = 0; j < 8; ++j) {
                const float x = ka[c][j];
                s += x * x;
                hk[j] = (f16)x;
                hv[j] = (f16)va[c][j];
            }
            sRed[w * 64 + scol] = s;
            *(f16x8*)&sXt[scol * 64 + (dbase ^ ((scol & 7) << 3))] = hk;
            *(f16x8*)&sVt[scol * 64 + (dbase ^ ((scol & 7) << 3))] = hv;
        }
        __syncthreads();

        // column norms (every wave writes identical values; deterministic)
        {
            float sqv = 0.f;
#pragma unroll
            for (int g = 0; g < 8; ++g) sqv += sRed[g * 64 + lane];
            sRedT[lane] = sqv;
        }

        // ---- z = K^T W^T per ri: C[l][r]; phi packed along l
#pragma unroll
        for (int ri = 0; ri < 2; ++ri) {
            f32x4 z[4];
#pragma unroll
            for (int lf = 0; lf < 4; ++lf) { f32x4 z0 = {0.f, 0.f, 0.f, 0.f}; z[lf] = z0; }
#pragma unroll
            for (int ks = 0; ks < 2; ++ks) {
                f16x8 bfr[4];
#pragma unroll
                for (int lf = 0; lf < 4; ++lf) {
                    const int row = 16 * lf + l15;
                    bfr[lf] = *(const f16x8*)&sXt[row * 64 + ((32 * ks + 8 * lhi) ^ ((row & 7) << 3))];
                }
#pragma unroll
                for (int lf = 0; lf < 4; ++lf)
                    z[lf] = __builtin_amdgcn_mfma_f32_16x16x32_f16(bfr[lf], wfrag[ri][ks], z[lf], 0, 0, 0);
            }
            const int r = 32 * w + 16 * ri + l15;
#pragma unroll
            for (int lf = 0; lf < 4; ++lf) {
                const f32x4 sq4 = *(const f32x4*)&sRedT[16 * lf + 4 * lhi];
                f16x4 ph;
#pragma unroll
                for (int j = 0; j < 4; ++j)
                    ph[j] = (f16)(kDnS * __expf(kAc + kBc * z[lf][j] - sq4[j]));
                const int lbase = 16 * lf + 4 * lhi;
                *(f16x4*)&sPhi[r * 64 + (lbase ^ ((r & 7) << 3))] = ph;
            }
        }
        __syncthreads();

        // ---- acc += phi @ V
#pragma unroll
        for (int ks = 0; ks < 2; ++ks) {
            f16x8 af[4], bf[2];
#pragma unroll
            for (int ai = 0; ai < 4; ++ai) {
                const int r = 64 * wr + 16 * ai + l15;
                af[ai] = *(const f16x8*)&sPhi[r * 64 + ((32 * ks + 8 * lhi) ^ ((r & 7) << 3))];
            }
#pragma unroll
            for (int di = 0; di < 2; ++di) {
                const int dv = 32 * wc + 16 * di + l15;
                bf[di] = *(const f16x8*)&sVt[dv * 64 + ((32 * ks + 8 * lhi) ^ ((dv & 7) << 3))];
            }
#pragma unroll
            for (int ai = 0; ai < 4; ++ai)
#pragma unroll
                for (int di = 0; di < 2; ++di)
                    acc[ai][di] = __builtin_amdgcn_mfma_f32_16x16x32_f16(af[ai], bf[di], acc[ai][di], 0, 0, 0);
        }
        if (c == 0) __syncthreads();
    }

    // ---- per-block partial, stored TRANSPOSED [dv][r]
    f16* po = partials + (size_t)blk * (kR * kDV);
#pragma unroll
    for (int ai = 0; ai < 4; ++ai)
#pragma unroll
        for (int di = 0; di < 2; ++di) {
            const int dv = 32 * wc + 16 * di + l15;
            f16x4 pk;
#pragma unroll
            for (int j = 0; j < 4; ++j) pk[j] = (f16)acc[ai][di][j];
            *(f16x4*)&po[dv * kR + 64 * wr + 16 * ai + 4 * lhi] = pk;
        }
}

// ---------------------------------------------------------------------------
// Kernel R: kvT[o] = sum over 512 slices of partials[s][o]  (o = dv*256 + r)
// 128 blocks x 512 thr: thread (slot=tid&15, g=tid>>4) sums 16 slices of its
// 8-output stripe; LDS combine of 32 groups.
// ---------------------------------------------------------------------------
__global__ __launch_bounds__(512)
void favor_reduce(const f16* __restrict__ partials, f16* __restrict__ kvT)
{
    __shared__ float sAcc[32][128];
    const int tid  = threadIdx.x;
    const int slot = tid & 15;
    const int g    = tid >> 4;
    const size_t obase = (size_t)blockIdx.x * 128 + slot * 8;

    float a[8] = {0.f, 0.f, 0.f, 0.f, 0.f, 0.f, 0.f, 0.f};
#pragma unroll 4
    for (int i = 0; i < 16; ++i) {
        const int s = g * 16 + i;
        const f16x8 v = *(const f16x8*)&partials[(size_t)s * (kR * kDV) + obase];
#pragma unroll
        for (int j = 0; j < 8; ++j) a[j] += (float)v[j];
    }
#pragma unroll
    for (int j = 0; j < 8; ++j) sAcc[g][slot * 8 + j] = a[j];
    __syncthreads();

    if (tid < 128) {
        float tot = 0.f;
#pragma unroll
        for (int gg = 0; gg < 32; ++gg) tot += sAcc[gg][tid];
        kvT[(size_t)blockIdx.x * 128 + tid] = (f16)tot;
    }
}

// ---------------------------------------------------------------------------
// Kernel B: out = (phi(Q)*2^10)^T @ kv, scaled 2^-20.
// 512 blocks x 2 chunks; kv staged to swizzled LDS (loads overlap chunk-0
// compute); Q for both chunks preloaded to registers.
// ---------------------------------------------------------------------------
__global__ __launch_bounds__(512, 2)
void favor_out(const float* __restrict__ Qg, const float* __restrict__ Wg,
               const f16* __restrict__ kvT, float* __restrict__ outg)
{
    __shared__ f16 sXt[64 * 64];     // Q chunk [l][d], swizzled
    __shared__ f16 sPhiT[64 * 256];  // [l][r], swizzled
    __shared__ f16 sKv[64 * 256];    // [dv][r], swizzled
    __shared__ float sRed[8 * 64];

    const int tid  = threadIdx.x;
    const int w    = tid >> 6;
    const int lane = tid & 63;
    const int l15  = lane & 15;
    const int lhi  = lane >> 4;
    const int blk  = blockIdx.x;
    const int lblk = blk * 128;

    const int scol  = lane;
    const int dbase = w * 8;

    // ---- issue Q loads (both chunks), then kv loads, then W (FIFO order)
    float qa[2][8];
#pragma unroll
    for (int c = 0; c < 2; ++c)
#pragma unroll
        for (int j = 0; j < 8; ++j)
            qa[c][j] = Qg[(dbase + j) * kL + lblk + c * 64 + scol];

    const int kdv  = tid >> 3;          // 0..63
    const int kslt = tid & 7;           // 0..7
    f16x8 kvld[4];
#pragma unroll
    for (int m = 0; m < 4; ++m)
        kvld[m] = *(const f16x8*)&kvT[kdv * kR + kslt * 32 + 8 * m];

    f16x8 wfrag[2][2];
#pragma unroll
    for (int ri = 0; ri < 2; ++ri)
#pragma unroll
        for (int ks = 0; ks < 2; ++ks) {
            const float* p = Wg + (32 * w + 16 * ri + l15) * kD + 32 * ks + 8 * lhi;
            f16x8 v;
#pragma unroll
            for (int j = 0; j < 8; ++j) v[j] = (f16)p[j];
            wfrag[ri][ks] = v;
        }

    const int lfo = w >> 1;
    const int dvh = w & 1;

#pragma unroll
    for (int c = 0; c < 2; ++c) {
        // ---- stage Q chunk c + norms; c==0: also stage kv -> LDS
        {
            float s = 0.f;
            f16x8 hq;
#pragma unroll
            for (int j = 0; j < 8; ++j) {
                const float x = qa[c][j];
                s += x * x;
                hq[j] = (f16)x;
            }
            sRed[w * 64 + scol] = s;
            *(f16x8*)&sXt[scol * 64 + (dbase ^ ((scol & 7) << 3))] = hq;
        }
        if (c == 0) {
#pragma unroll
            for (int m = 0; m < 4; ++m)
                *(f16x8*)&sKv[kdv * kR + ((kslt * 32 + 8 * m) ^ ((kdv & 7) << 3))] = kvld[m];
        }
        __syncthreads();

        float sqv = 0.f;
#pragma unroll
        for (int g = 0; g < 8; ++g) sqv += sRed[g * 64 + lane];
        float sqs[4];
#pragma unroll
        for (int lf = 0; lf < 4; ++lf) sqs[lf] = __shfl(sqv, lf * 16 + l15, 64);

        // ---- z = W @ Q per ri: C[r][l]; phi packs 4 consecutive r -> [l][r]
#pragma unroll
        for (int ri = 0; ri < 2; ++ri) {
            f32x4 z[4];
#pragma unroll
            for (int lf = 0; lf < 4; ++lf) { f32x4 z0 = {0.f, 0.f, 0.f, 0.f}; z[lf] = z0; }
#pragma unroll
            for (int ks = 0; ks < 2; ++ks) {
                f16x8 bfr[4];
#pragma unroll
                for (int lf = 0; lf < 4; ++lf) {
                    const int row = 16 * lf + l15;
                    bfr[lf] = *(const f16x8*)&sXt[row * 64 + ((32 * ks + 8 * lhi) ^ ((row & 7) << 3))];
                }
#pragma unroll
                for (int lf = 0; lf < 4; ++lf)
                    z[lf] = __builtin_amdgcn_mfma_f32_16x16x32_f16(wfrag[ri][ks], bfr[lf], z[lf], 0, 0, 0);
            }
            const int r0 = 32 * w + 16 * ri + 4 * lhi;
#pragma unroll
            for (int lf = 0; lf < 4; ++lf) {
                const int lc = 16 * lf + l15;
                f16x4 ph;
#pragma unroll
                for (int j = 0; j < 4; ++j)
                    ph[j] = (f16)(kDnS * __expf(kAc + kBc * z[lf][j] - sqs[lf]));
                *(f16x4*)&sPhiT[lc * 256 + (r0 ^ ((lc & 7) << 3))] = ph;
            }
        }
        __syncthreads();

        // ---- out tile = phiQ^T @ kv (kv from swizzled LDS)
        f32x4 o2[2];
        { f32x4 z0 = {0.f, 0.f, 0.f, 0.f}; o2[0] = z0; o2[1] = z0; }
        const int lrow = 16 * lfo + l15;
#pragma unroll
        for (int ks = 0; ks < 8; ++ks) {
            const f16x8 af = *(const f16x8*)&sPhiT[lrow * 256 + ((32 * ks + 8 * lhi) ^ ((lrow & 7) << 3))];
#pragma unroll
            for (int di = 0; di < 2; ++di) {
                const int dv = 32 * dvh + 16 * di + l15;
                const f16x8 bf = *(const f16x8*)&sKv[dv * kR + ((32 * ks + 8 * lhi) ^ ((dv & 7) << 3))];
                o2[di] = __builtin_amdgcn_mfma_f32_16x16x32_f16(af, bf, o2[di], 0, 0, 0);
            }
        }
        const int l0 = lblk + c * 64;
#pragma unroll
        for (int di = 0; di < 2; ++di)
#pragma unroll
            for (int j = 0; j < 4; ++j) {
                const int ll = 16 * lfo + 4 * lhi + j;
                const int dv = 32 * dvh + 16 * di + l15;
                outg[(size_t)(l0 + ll) * kDV + dv] = o2[di][j] * kOutScale;
            }
        if (c == 0) __syncthreads();
    }
}

extern "C" void kernel_launch(void* const* d_in, const int* in_sizes, int n_in,
                              void* d_out, int out_size, void* d_ws, size_t ws_size,
                              hipStream_t stream)
{
    const float* Q = (const float*)d_in[0];
    const float* K = (const float*)d_in[1];
    const float* V = (const float*)d_in[2];
    const float* W = (const float*)d_in[3];
    float* out = (float*)d_out;

    f16* partials = (f16*)d_ws;  // 512 * 16384 f16 = 16 MiB
    f16* kvT = (f16*)((char*)d_ws + (size_t)kABlocks * kR * kDV * sizeof(f16));

    favor_kv<<<kABlocks, 512, 0, stream>>>(K, V, W, partials);
    favor_reduce<<<kRBlocks, 512, 0, stream>>>(partials, kvT);
    favor_out<<<kBBlocks, 512, 0, stream>>>(Q, W, kvT, out);

    (void)in_sizes; (void)n_in; (void)out_size; (void)ws_size;
}

// Round 7
// 41.628 us; speedup vs baseline: 6.1878x; 1.0155x over previous
//
#include <hip/hip_runtime.h>

typedef _Float16 f16;
typedef __attribute__((ext_vector_type(8))) _Float16 f16x8;
typedef __attribute__((ext_vector_type(4))) _Float16 f16x4;
typedef __attribute__((ext_vector_type(4))) float f32x4;

// Barrier that does NOT drain vmcnt: LDS ordering via lgkmcnt(0), global
// prefetches stay in flight (avoids __syncthreads' vmcnt(0) drain).
#define BARRIER()                                              \
    do {                                                       \
        asm volatile("s_waitcnt lgkmcnt(0)" ::: "memory");     \
        __builtin_amdgcn_s_barrier();                          \
        __builtin_amdgcn_sched_barrier(0);                     \
    } while (0)

namespace {
constexpr int kL   = 65536;
constexpr int kR   = 256;
constexpr int kD   = 64;
constexpr int kDV  = 64;

constexpr int kABlocks = 512;   // 128 cols each (2 chunks of 64)
constexpr int kBBlocks = 512;   // 128 cols each (2 chunks of 64)
constexpr int kRBlocks = 128;   // 128 outputs each

constexpr float kAc  = 0.1f;
constexpr float kBc  = 0.7745966692414834f;      // sqrt(0.6)
constexpr float kDnS = 0.2888816545234944f;      // 0.6^16 * 2^10 (PHI_SCALE folded)
constexpr float kOutScale = 9.5367431640625e-7f; // 2^-20 undoes PHI_SCALE^2
}

// ---------------------------------------------------------------------------
// Kernel A: partials[blk][dv][r] (f16) = (phi(K_cols)*2^10 @ V_cols)^T
// Both chunks' K/V preloaded to registers at entry; barriers don't drain vmcnt
// so chunk-1 loads stay in flight across chunk-0 compute.
// ---------------------------------------------------------------------------
__global__ __launch_bounds__(512, 2)
void favor_kv(const float* __restrict__ Kg, const float* __restrict__ Vg,
              const float* __restrict__ Wg, f16* __restrict__ partials)
{
    __shared__ f16 sXt[64 * 64];    // K chunk [l][d], swizzled
    __shared__ f16 sVt[64 * 64];    // V chunk [dv][l], swizzled
    __shared__ f16 sPhi[256 * 64];  // [r][l], swizzled
    __shared__ float sRed[8 * 64];  // per-wave norm partials
    __shared__ float sRedT[64];     // total column norms

    const int tid  = threadIdx.x;
    const int w    = tid >> 6;
    const int lane = tid & 63;
    const int l15  = lane & 15;
    const int lhi  = lane >> 4;
    const int blk  = blockIdx.x;
    const int lblk = blk * 128;

    const int scol  = lane;
    const int dbase = w * 8;

    // ---- issue ALL global loads up front (FIFO vmcnt: chunk0 first)
    float ka[2][8], va[2][8];
#pragma unroll
    for (int c = 0; c < 2; ++c) {
        const int l0 = lblk + c * 64;
#pragma unroll
        for (int j = 0; j < 8; ++j) ka[c][j] = Kg[(dbase + j) * kL + l0 + scol];
#pragma unroll
        for (int j = 0; j < 8; ++j) va[c][j] = Vg[(size_t)(l0 + dbase + j) * kDV + scol];
    }

    // W fragments (B-operand: col = l15 -> r, k = 8*lhi+j -> d)
    f16x8 wfrag[2][2];
#pragma unroll
    for (int ri = 0; ri < 2; ++ri)
#pragma unroll
        for (int ks = 0; ks < 2; ++ks) {
            const float* p = Wg + (32 * w + 16 * ri + l15) * kD + 32 * ks + 8 * lhi;
            f16x8 v;
#pragma unroll
            for (int j = 0; j < 8; ++j) v[j] = (f16)p[j];
            wfrag[ri][ks] = v;
        }

    f32x4 acc[4][2];
#pragma unroll
    for (int a = 0; a < 4; ++a)
#pragma unroll
        for (int d = 0; d < 2; ++d) { f32x4 z0 = {0.f, 0.f, 0.f, 0.f}; acc[a][d] = z0; }

    const int wr = w >> 1;     // PV r-group (64 rows)
    const int wc = w & 1;      // PV dv half (32 cols)

#pragma unroll
    for (int c = 0; c < 2; ++c) {
        // ---- stage chunk c from regs (f32 -> f16, transposed, swizzled)
        {
            float s = 0.f;
            f16x8 hk, hv;
#pragma unroll
            for (int j = 0; j < 8; ++j) {
                const float x = ka[c][j];
                s += x * x;
                hk[j] = (f16)x;
                hv[j] = (f16)va[c][j];
            }
            sRed[w * 64 + scol] = s;
            *(f16x8*)&sXt[scol * 64 + (dbase ^ ((scol & 7) << 3))] = hk;
            *(f16x8*)&sVt[scol * 64 + (dbase ^ ((scol & 7) << 3))] = hv;
        }
        BARRIER();

        // column norms (every wave writes identical values; deterministic)
        {
            float sqv = 0.f;
#pragma unroll
            for (int g = 0; g < 8; ++g) sqv += sRed[g * 64 + lane];
            sRedT[lane] = sqv;
        }

        // ---- z = K^T W^T per ri: C[l][r]; phi packed along l
#pragma unroll
        for (int ri = 0; ri < 2; ++ri) {
            f32x4 z[4];
#pragma unroll
            for (int lf = 0; lf < 4; ++lf) { f32x4 z0 = {0.f, 0.f, 0.f, 0.f}; z[lf] = z0; }
            __builtin_amdgcn_s_setprio(1);
#pragma unroll
            for (int ks = 0; ks < 2; ++ks) {
                f16x8 bfr[4];
#pragma unroll
                for (int lf = 0; lf < 4; ++lf) {
                    const int row = 16 * lf + l15;
                    bfr[lf] = *(const f16x8*)&sXt[row * 64 + ((32 * ks + 8 * lhi) ^ ((row & 7) << 3))];
                }
#pragma unroll
                for (int lf = 0; lf < 4; ++lf)
                    z[lf] = __builtin_amdgcn_mfma_f32_16x16x32_f16(bfr[lf], wfrag[ri][ks], z[lf], 0, 0, 0);
            }
            __builtin_amdgcn_s_setprio(0);
            const int r = 32 * w + 16 * ri + l15;
#pragma unroll
            for (int lf = 0; lf < 4; ++lf) {
                const f32x4 sq4 = *(const f32x4*)&sRedT[16 * lf + 4 * lhi];
                f16x4 ph;
#pragma unroll
                for (int j = 0; j < 4; ++j)
                    ph[j] = (f16)(kDnS * __expf(kAc + kBc * z[lf][j] - sq4[j]));
                const int lbase = 16 * lf + 4 * lhi;
                *(f16x4*)&sPhi[r * 64 + (lbase ^ ((r & 7) << 3))] = ph;
            }
        }
        BARRIER();

        // ---- acc += phi @ V
        __builtin_amdgcn_s_setprio(1);
#pragma unroll
        for (int ks = 0; ks < 2; ++ks) {
            f16x8 af[4], bf[2];
#pragma unroll
            for (int ai = 0; ai < 4; ++ai) {
                const int r = 64 * wr + 16 * ai + l15;
                af[ai] = *(const f16x8*)&sPhi[r * 64 + ((32 * ks + 8 * lhi) ^ ((r & 7) << 3))];
            }
#pragma unroll
            for (int di = 0; di < 2; ++di) {
                const int dv = 32 * wc + 16 * di + l15;
                bf[di] = *(const f16x8*)&sVt[dv * 64 + ((32 * ks + 8 * lhi) ^ ((dv & 7) << 3))];
            }
#pragma unroll
            for (int ai = 0; ai < 4; ++ai)
#pragma unroll
                for (int di = 0; di < 2; ++di)
                    acc[ai][di] = __builtin_amdgcn_mfma_f32_16x16x32_f16(af[ai], bf[di], acc[ai][di], 0, 0, 0);
        }
        __builtin_amdgcn_s_setprio(0);
        if (c == 0) BARRIER();
    }

    // ---- per-block partial, stored TRANSPOSED [dv][r]
    f16* po = partials + (size_t)blk * (kR * kDV);
#pragma unroll
    for (int ai = 0; ai < 4; ++ai)
#pragma unroll
        for (int di = 0; di < 2; ++di) {
            const int dv = 32 * wc + 16 * di + l15;
            f16x4 pk;
#pragma unroll
            for (int j = 0; j < 4; ++j) pk[j] = (f16)acc[ai][di][j];
            *(f16x4*)&po[dv * kR + 64 * wr + 16 * ai + 4 * lhi] = pk;
        }
}

// ---------------------------------------------------------------------------
// Kernel R: kvT[o] = sum over 512 slices of partials[s][o]  (o = dv*256 + r)
// ---------------------------------------------------------------------------
__global__ __launch_bounds__(512)
void favor_reduce(const f16* __restrict__ partials, f16* __restrict__ kvT)
{
    __shared__ float sAcc[32][128];
    const int tid  = threadIdx.x;
    const int slot = tid & 15;
    const int g    = tid >> 4;
    const size_t obase = (size_t)blockIdx.x * 128 + slot * 8;

    float a[8] = {0.f, 0.f, 0.f, 0.f, 0.f, 0.f, 0.f, 0.f};
#pragma unroll 4
    for (int i = 0; i < 16; ++i) {
        const int s = g * 16 + i;
        const f16x8 v = *(const f16x8*)&partials[(size_t)s * (kR * kDV) + obase];
#pragma unroll
        for (int j = 0; j < 8; ++j) a[j] += (float)v[j];
    }
#pragma unroll
    for (int j = 0; j < 8; ++j) sAcc[g][slot * 8 + j] = a[j];
    __syncthreads();

    if (tid < 128) {
        float tot = 0.f;
#pragma unroll
        for (int gg = 0; gg < 32; ++gg) tot += sAcc[gg][tid];
        kvT[(size_t)blockIdx.x * 128 + tid] = (f16)tot;
    }
}

// ---------------------------------------------------------------------------
// Kernel B: out = (phi(Q)*2^10)^T @ kv, scaled 2^-20.
// 512 blocks x 2 chunks; kv staged to swizzled LDS; Q for both chunks
// preloaded; barriers don't drain vmcnt.
// ---------------------------------------------------------------------------
__global__ __launch_bounds__(512, 2)
void favor_out(const float* __restrict__ Qg, const float* __restrict__ Wg,
               const f16* __restrict__ kvT, float* __restrict__ outg)
{
    __shared__ f16 sXt[64 * 64];     // Q chunk [l][d], swizzled
    __shared__ f16 sPhiT[64 * 256];  // [l][r], swizzled
    __shared__ f16 sKv[64 * 256];    // [dv][r], swizzled
    __shared__ float sRed[8 * 64];

    const int tid  = threadIdx.x;
    const int w    = tid >> 6;
    const int lane = tid & 63;
    const int l15  = lane & 15;
    const int lhi  = lane >> 4;
    const int blk  = blockIdx.x;
    const int lblk = blk * 128;

    const int scol  = lane;
    const int dbase = w * 8;

    // ---- issue Q loads (both chunks), then kv loads, then W (FIFO order)
    float qa[2][8];
#pragma unroll
    for (int c = 0; c < 2; ++c)
#pragma unroll
        for (int j = 0; j < 8; ++j)
            qa[c][j] = Qg[(dbase + j) * kL + lblk + c * 64 + scol];

    const int kdv  = tid >> 3;          // 0..63
    const int kslt = tid & 7;           // 0..7
    f16x8 kvld[4];
#pragma unroll
    for (int m = 0; m < 4; ++m)
        kvld[m] = *(const f16x8*)&kvT[kdv * kR + kslt * 32 + 8 * m];

    f16x8 wfrag[2][2];
#pragma unroll
    for (int ri = 0; ri < 2; ++ri)
#pragma unroll
        for (int ks = 0; ks < 2; ++ks) {
            const float* p = Wg + (32 * w + 16 * ri + l15) * kD + 32 * ks + 8 * lhi;
            f16x8 v;
#pragma unroll
            for (int j = 0; j < 8; ++j) v[j] = (f16)p[j];
            wfrag[ri][ks] = v;
        }

    const int lfo = w >> 1;
    const int dvh = w & 1;

#pragma unroll
    for (int c = 0; c < 2; ++c) {
        // ---- stage Q chunk c + norms; c==0: also stage kv -> LDS
        {
            float s = 0.f;
            f16x8 hq;
#pragma unroll
            for (int j = 0; j < 8; ++j) {
                const float x = qa[c][j];
                s += x * x;
                hq[j] = (f16)x;
            }
            sRed[w * 64 + scol] = s;
            *(f16x8*)&sXt[scol * 64 + (dbase ^ ((scol & 7) << 3))] = hq;
        }
        if (c == 0) {
#pragma unroll
            for (int m = 0; m < 4; ++m)
                *(f16x8*)&sKv[kdv * kR + ((kslt * 32 + 8 * m) ^ ((kdv & 7) << 3))] = kvld[m];
        }
        BARRIER();

        float sqv = 0.f;
#pragma unroll
        for (int g = 0; g < 8; ++g) sqv += sRed[g * 64 + lane];
        float sqs[4];
#pragma unroll
        for (int lf = 0; lf < 4; ++lf) sqs[lf] = __shfl(sqv, lf * 16 + l15, 64);

        // ---- z = W @ Q per ri: C[r][l]; phi packs 4 consecutive r -> [l][r]
#pragma unroll
        for (int ri = 0; ri < 2; ++ri) {
            f32x4 z[4];
#pragma unroll
            for (int lf = 0; lf < 4; ++lf) { f32x4 z0 = {0.f, 0.f, 0.f, 0.f}; z[lf] = z0; }
            __builtin_amdgcn_s_setprio(1);
#pragma unroll
            for (int ks = 0; ks < 2; ++ks) {
                f16x8 bfr[4];
#pragma unroll
                for (int lf = 0; lf < 4; ++lf) {
                    const int row = 16 * lf + l15;
                    bfr[lf] = *(const f16x8*)&sXt[row * 64 + ((32 * ks + 8 * lhi) ^ ((row & 7) << 3))];
                }
#pragma unroll
                for (int lf = 0; lf < 4; ++lf)
                    z[lf] = __builtin_amdgcn_mfma_f32_16x16x32_f16(wfrag[ri][ks], bfr[lf], z[lf], 0, 0, 0);
            }
            __builtin_amdgcn_s_setprio(0);
            const int r0 = 32 * w + 16 * ri + 4 * lhi;
#pragma unroll
            for (int lf = 0; lf < 4; ++lf) {
                const int lc = 16 * lf + l15;
                f16x4 ph;
#pragma unroll
                for (int j = 0; j < 4; ++j)
                    ph[j] = (f16)(kDnS * __expf(kAc + kBc * z[lf][j] - sqs[lf]));
                *(f16x4*)&sPhiT[lc * 256 + (r0 ^ ((lc & 7) << 3))] = ph;
            }
        }
        BARRIER();

        // ---- out tile = phiQ^T @ kv (kv from swizzled LDS)
        f32x4 o2[2];
        { f32x4 z0 = {0.f, 0.f, 0.f, 0.f}; o2[0] = z0; o2[1] = z0; }
        const int lrow = 16 * lfo + l15;
        __builtin_amdgcn_s_setprio(1);
#pragma unroll
        for (int ks = 0; ks < 8; ++ks) {
            const f16x8 af = *(const f16x8*)&sPhiT[lrow * 256 + ((32 * ks + 8 * lhi) ^ ((lrow & 7) << 3))];
#pragma unroll
            for (int di = 0; di < 2; ++di) {
                const int dv = 32 * dvh + 16 * di + l15;
                const f16x8 bf = *(const f16x8*)&sKv[dv * kR + ((32 * ks + 8 * lhi) ^ ((dv & 7) << 3))];
                o2[di] = __builtin_amdgcn_mfma_f32_16x16x32_f16(af, bf, o2[di], 0, 0, 0);
            }
        }
        __builtin_amdgcn_s_setprio(0);
        const int l0 = lblk + c * 64;
#pragma unroll
        for (int di = 0; di < 2; ++di)
#pragma unroll
            for (int j = 0; j < 4; ++j) {
                const int ll = 16 * lfo + 4 * lhi + j;
                const int dv = 32 * dvh + 16 * di + l15;
                outg[(size_t)(l0 + ll) * kDV + dv] = o2[di][j] * kOutScale;
            }
        if (c == 0) BARRIER();
    }
}

extern "C" void kernel_launch(void* const* d_in, const int* in_sizes, int n_in,
                              void* d_out, int out_size, void* d_ws, size_t ws_size,
                              hipStream_t stream)
{
    const float* Q = (const float*)d_in[0];
    const float* K = (const float*)d_in[1];
    const float* V = (const float*)d_in[2];
    const float* W = (const float*)d_in[3];
    float* out = (float*)d_out;

    f16* partials = (f16*)d_ws;  // 512 * 16384 f16 = 16 MiB
    f16* kvT = (f16*)((char*)d_ws + (size_t)kABlocks * kR * kDV * sizeof(f16));

    favor_kv<<<kABlocks, 512, 0, stream>>>(K, V, W, partials);
    favor_reduce<<<kRBlocks, 512, 0, stream>>>(partials, kvT);
    favor_out<<<kBBlocks, 512, 0, stream>>>(Q, W, kvT, out);

    (void)in_sizes; (void)n_in; (void)out_size; (void)ws_size;
}